// Round 1
// baseline (1248.071 us; speedup 1.0000x reference)
//
#include <hip/hip_runtime.h>

// Problem constants (from reference)
#define BATCH      262144
#define PEP_ROWS   9        // only rows 0..8 of the 15 are ever used by the mask
#define REC_STRIDE 300      // 15*20 floats per peptide record
#define A          20       // ALPHABET
#define P          34       // NUM_POCKETS
#define F          9        // FILTER
#define OUTW       28       // A + F - 1
#define BPB        8        // batches per block
#define PAIRS      (BPB * P)        // 272 (b,p) pairs per block
#define NTHREADS   256
#define OUT_PER_BLOCK (PAIRS * OUTW)  // 7616 floats

__global__ __launch_bounds__(NTHREADS, 4)
void pep_pocket_conv(const float* __restrict__ pep,
                     const int*   __restrict__ pocket,
                     const float* __restrict__ kern,
                     float*       __restrict__ out)
{
    // LDS: 5760 + 720 + 1088 + 31552 = 39120 B -> 4 blocks/CU
    __shared__ float sPep[BPB * PEP_ROWS * A];   // [8][180]
    __shared__ float sK[A * F];                  // [20][9]
    __shared__ int   sIdx[PAIRS];                // 272
    __shared__ float sOut[PAIRS * (OUTW + 1)];   // pad 28->29: conflict-free staging

    const int t = threadIdx.x;
    const int b0 = blockIdx.x * BPB;
    const int pairBase = b0 * P;                 // flat idx into pocket_encoding too

    // Stage the shared 20x9 kernel
    if (t < A * F) sK[t] = kern[t];

    // Stage pocket indices (contiguous: flat pair index == b*34+p)
    for (int i = t; i < PAIRS; i += NTHREADS) sIdx[i] = pocket[pairBase + i];

    // Stage peptide rows 0..8 per batch as float4 (45 vec4 per batch; 1200B
    // record stride keeps 16B alignment)
    for (int i = t; i < BPB * 45; i += NTHREADS) {
        int lb = i / 45, v = i % 45;
        const float4 x = *(const float4*)(pep + (b0 + lb) * REC_STRIDE + v * 4);
        *(float4*)(&sPep[lb * (PEP_ROWS * A) + v * 4]) = x;
    }
    __syncthreads();

    // One thread per (b,p) pair: full conv in registers
    for (int round = 0; round < 2; ++round) {
        const int pl = t + round * NTHREADS;
        if (pl < PAIRS) {
            const int lb = pl / P;
            const int p  = pl % P;
            const int r  = p % 9;          // first mask row
            const int j2 = 3 * (p % 3);    // second mask row (== r only when r==0)
            const float* base = &sPep[lb * (PEP_ROWS * A)];

            float a[A];
            #pragma unroll
            for (int j = 0; j < A; ++j) {
                float v = base[r * A + j];
                if (j2 != r) v += base[j2 * A + j];
                a[j] = v;
            }

            const int c = sIdx[pl];
            float kf[F];
            #pragma unroll
            for (int f = 0; f < F; ++f) kf[f] = sK[c * F + f];

            float acc[OUTW];
            #pragma unroll
            for (int k = 0; k < OUTW; ++k) acc[k] = 0.f;
            #pragma unroll
            for (int f = 0; f < F; ++f) {
                #pragma unroll
                for (int j = 0; j < A; ++j)
                    acc[f + j] += kf[f] * a[j];
            }

            float* so = &sOut[pl * (OUTW + 1)];
            #pragma unroll
            for (int k = 0; k < OUTW; ++k) so[k] = acc[k];
        }
    }
    __syncthreads();

    // Fully-coalesced block writeout: 30464 contiguous bytes
    const int outBase = pairBase * OUTW;
    for (int i = t; i < OUT_PER_BLOCK; i += NTHREADS) {
        const int pl = i / OUTW, k = i - pl * OUTW;
        out[outBase + i] = sOut[pl * (OUTW + 1) + k];
    }
}

extern "C" void kernel_launch(void* const* d_in, const int* in_sizes, int n_in,
                              void* d_out, int out_size, void* d_ws, size_t ws_size,
                              hipStream_t stream) {
    const float* pep    = (const float*)d_in[0];  // [B,15,20] fp32
    const int*   pocket = (const int*)d_in[1];    // [B,34] int32
    const float* kern   = (const float*)d_in[2];  // [20,9] fp32
    float* out = (float*)d_out;                   // [B,34,28] fp32

    const int grid = BATCH / BPB;                 // 32768
    pep_pocket_conv<<<grid, NTHREADS, 0, stream>>>(pep, pocket, kern, out);
}